// Round 1
// baseline (1253.766 us; speedup 1.0000x reference)
//
#include <hip/hip_runtime.h>

#define NN 100000
#define NE 1600000
#define DF 128
#define DOUT 64
#define NG 128

// ---------------- graph preprocessing ----------------

__global__ void k_zero(int* __restrict__ cnt) {
    int i = blockIdx.x * blockDim.x + threadIdx.x;
    if (i < NN) cnt[i] = 0;
}

__global__ void k_hist(const int* __restrict__ dst, int* __restrict__ cnt) {
    int i = blockIdx.x * blockDim.x + threadIdx.x;
    if (i < NE) atomicAdd(&cnt[dst[i]], 1);
}

// single-block scan: cnt -> rowptr (exclusive), cursor copy, dinv = rsqrt(cnt+1)
__global__ __launch_bounds__(1024) void k_scan(const int* __restrict__ cnt,
                                               int* __restrict__ rowptr,
                                               int* __restrict__ cursor,
                                               float* __restrict__ dinv) {
    __shared__ int sums[1024];
    int t = threadIdx.x;
    const int CH = (NN + 1023) / 1024;  // 98
    int base = t * CH;
    int s = 0;
    for (int i = 0; i < CH; i++) {
        int idx = base + i;
        if (idx < NN) s += cnt[idx];
    }
    sums[t] = s;
    __syncthreads();
    for (int off = 1; off < 1024; off <<= 1) {
        int add = (t >= off) ? sums[t - off] : 0;
        __syncthreads();
        sums[t] += add;
        __syncthreads();
    }
    int run = sums[t] - s;  // exclusive prefix
    for (int i = 0; i < CH; i++) {
        int idx = base + i;
        if (idx < NN) {
            rowptr[idx] = run;
            cursor[idx] = run;
            int c = cnt[idx];
            run += c;
            dinv[idx] = rsqrtf((float)(c + 1));  // +1 self-loop
        }
    }
    if (t == 0) rowptr[NN] = sums[1023];
}

__global__ void k_fill(const int* __restrict__ src, const int* __restrict__ dst,
                       int* __restrict__ cursor, int* __restrict__ col) {
    int i = blockIdx.x * blockDim.x + threadIdx.x;
    if (i < NE) {
        int d = dst[i];
        int p = atomicAdd(&cursor[d], 1);
        col[p] = src[i];
    }
}

// ---------------- per-layer compute ----------------

// out[n][f] = dinv[n] * sum_k X[n][k] * W[k][f]   (64-row x 64-col tile per block)
__global__ __launch_bounds__(256) void k_gemm(const float* __restrict__ X,
                                              const float* __restrict__ W,
                                              const float* __restrict__ dinv,
                                              float* __restrict__ out) {
    __shared__ float xs[64][132];   // padded: +4 floats keeps 16B alignment, breaks bank stride
    __shared__ float ws[128][64];
    int t = threadIdx.x;
    int row0 = blockIdx.x * 64;
    int cb = blockIdx.y * 64;

    // load W half-tile: 128x64 floats = 2048 float4
    for (int i = 0; i < 8; i++) {
        int li = t + i * 256;
        int k = li >> 4;
        int fq = li & 15;
        float4 v = *(const float4*)&W[k * DF + cb + fq * 4];
        *(float4*)&ws[k][fq * 4] = v;
    }
    // load X tile: 64 rows x 128
    for (int i = 0; i < 8; i++) {
        int li = t + i * 256;
        int r = li >> 5;
        int kq = li & 31;
        int gr = row0 + r;
        float4 v = make_float4(0.f, 0.f, 0.f, 0.f);
        if (gr < NN) v = *(const float4*)&X[gr * DF + kq * 4];
        *(float4*)&xs[r][kq * 4] = v;
    }
    __syncthreads();

    int tx = t & 15, ty = t >> 4;
    float acc[4][4] = {};
#pragma unroll 4
    for (int k = 0; k < 128; k++) {
        float4 wv = *(const float4*)&ws[k][tx * 4];
        float x0 = xs[ty * 4 + 0][k];
        float x1 = xs[ty * 4 + 1][k];
        float x2 = xs[ty * 4 + 2][k];
        float x3 = xs[ty * 4 + 3][k];
        acc[0][0] += x0 * wv.x; acc[0][1] += x0 * wv.y; acc[0][2] += x0 * wv.z; acc[0][3] += x0 * wv.w;
        acc[1][0] += x1 * wv.x; acc[1][1] += x1 * wv.y; acc[1][2] += x1 * wv.z; acc[1][3] += x1 * wv.w;
        acc[2][0] += x2 * wv.x; acc[2][1] += x2 * wv.y; acc[2][2] += x2 * wv.z; acc[2][3] += x2 * wv.w;
        acc[3][0] += x3 * wv.x; acc[3][1] += x3 * wv.y; acc[3][2] += x3 * wv.z; acc[3][3] += x3 * wv.w;
    }

    for (int j = 0; j < 4; j++) {
        int r = row0 + ty * 4 + j;
        if (r < NN) {
            float dv = dinv[r];
            float4 o;
            o.x = acc[j][0] * dv; o.y = acc[j][1] * dv;
            o.z = acc[j][2] * dv; o.w = acc[j][3] * dv;
            *(float4*)&out[r * DF + cb + tx * 4] = o;
        }
    }
}

// out[n] = relu(dinv[n] * (hs[n] + sum_{e in row n} hs[col[e]]) + b)
// one wave per node, lane handles 2 features (float2)
__global__ __launch_bounds__(256) void k_agg(const float* __restrict__ hs,
                                             const int* __restrict__ rowptr,
                                             const int* __restrict__ col,
                                             const float* __restrict__ dinv,
                                             const float* __restrict__ b,
                                             float* __restrict__ out) {
    int n = (int)((blockIdx.x * (size_t)blockDim.x + threadIdx.x) >> 6);
    int lane = threadIdx.x & 63;
    if (n >= NN) return;
    int f = lane * 2;
    float2 acc = *(const float2*)&hs[(size_t)n * DF + f];  // self-loop term
    int e = rowptr[n];
    int e1 = rowptr[n + 1];
    for (; e + 4 <= e1; e += 4) {
        int s0 = col[e], s1 = col[e + 1], s2 = col[e + 2], s3 = col[e + 3];
        float2 a0 = *(const float2*)&hs[(size_t)s0 * DF + f];
        float2 a1 = *(const float2*)&hs[(size_t)s1 * DF + f];
        float2 a2 = *(const float2*)&hs[(size_t)s2 * DF + f];
        float2 a3 = *(const float2*)&hs[(size_t)s3 * DF + f];
        acc.x += (a0.x + a1.x) + (a2.x + a3.x);
        acc.y += (a0.y + a1.y) + (a2.y + a3.y);
    }
    for (; e < e1; e++) {
        int s = col[e];
        float2 a = *(const float2*)&hs[(size_t)s * DF + f];
        acc.x += a.x; acc.y += a.y;
    }
    float dv = dinv[n];
    float2 bb = *(const float2*)&b[f];
    float2 o;
    o.x = fmaxf(dv * acc.x + bb.x, 0.f);
    o.y = fmaxf(dv * acc.y + bb.y, 0.f);
    *(float2*)&out[(size_t)n * DF + f] = o;
}

// ---------------- pooling + FC ----------------

__global__ void k_bounds(const int* __restrict__ batch, int* __restrict__ gstart) {
    int g = threadIdx.x;
    if (g > NG) return;
    int lo = 0, hi = NN;
    while (lo < hi) {
        int mid = (lo + hi) >> 1;
        if (batch[mid] < g) lo = mid + 1; else hi = mid;
    }
    gstart[g] = lo;
}

__global__ __launch_bounds__(256) void k_pool(const float* __restrict__ h,
                                              const int* __restrict__ gstart,
                                              float* __restrict__ pooled) {
    __shared__ float red[256];
    int g = blockIdx.x;
    int t = threadIdx.x;
    int f = t & 127, half = t >> 7;
    int s = gstart[g], epos = gstart[g + 1];
    float acc = 0.f;
    for (int n = s + half; n < epos; n += 2) acc += h[(size_t)n * DF + f];
    red[t] = acc;
    __syncthreads();
    if (t < 128) {
        int c = epos - s;
        float tot = red[t] + red[t + 128];
        pooled[g * DF + f] = tot / (float)max(c, 1);
    }
}

__global__ __launch_bounds__(64) void k_fc(const float* __restrict__ pooled,
                                           const float* __restrict__ Wfc,
                                           const float* __restrict__ bfc,
                                           float* __restrict__ out) {
    int g = blockIdx.x;
    int o = threadIdx.x;
    float acc = bfc[o];
    for (int k = 0; k < DF; k++) acc += pooled[g * DF + k] * Wfc[k * DOUT + o];
    out[g * DOUT + o] = acc;
}

// ---------------- launch ----------------

extern "C" void kernel_launch(void* const* d_in, const int* in_sizes, int n_in,
                              void* d_out, int out_size, void* d_ws, size_t ws_size,
                              hipStream_t stream) {
    const float* x     = (const float*)d_in[0];
    const int*   ei    = (const int*)d_in[1];   // [2, NE] flattened: src then dst
    const int*   batch = (const int*)d_in[2];
    const float* W1 = (const float*)d_in[3];
    const float* b1 = (const float*)d_in[4];
    const float* W2 = (const float*)d_in[5];
    const float* b2 = (const float*)d_in[6];
    const float* W3 = (const float*)d_in[7];
    const float* b3 = (const float*)d_in[8];
    const float* Wfc = (const float*)d_in[9];
    const float* bfc = (const float*)d_in[10];
    float* out = (float*)d_out;

    char* p = (char*)d_ws;
    float* bufA = (float*)p;           p += (size_t)NN * DF * sizeof(float);
    float* bufB = (float*)p;           p += (size_t)NN * DF * sizeof(float);
    float* dinv = (float*)p;           p += (size_t)NN * sizeof(float);
    int* cnt    = (int*)p;             p += (size_t)NN * sizeof(int);
    int* rowptr = (int*)p;             p += (size_t)(NN + 4) * sizeof(int);
    int* cursor = (int*)p;             p += (size_t)NN * sizeof(int);
    int* col    = (int*)p;             p += (size_t)NE * sizeof(int);
    int* gstart = (int*)p;             p += (size_t)(NG + 4) * sizeof(int);
    float* pooled = (float*)p;         p += (size_t)NG * DF * sizeof(float);

    const int* e_src = ei;
    const int* e_dst = ei + NE;

    // graph preprocessing (CSR by dst, no self-loop edges stored)
    k_zero<<<(NN + 255) / 256, 256, 0, stream>>>(cnt);
    k_hist<<<(NE + 255) / 256, 256, 0, stream>>>(e_dst, cnt);
    k_scan<<<1, 1024, 0, stream>>>(cnt, rowptr, cursor, dinv);
    k_fill<<<(NE + 255) / 256, 256, 0, stream>>>(e_src, e_dst, cursor, col);

    dim3 ggrid((NN + 63) / 64, 2);
    int agg_blocks = (NN + 3) / 4;  // one wave per node, 4 waves/block

    // layer 1
    k_gemm<<<ggrid, 256, 0, stream>>>(x, W1, dinv, bufA);
    k_agg<<<agg_blocks, 256, 0, stream>>>(bufA, rowptr, col, dinv, b1, bufB);
    // layer 2
    k_gemm<<<ggrid, 256, 0, stream>>>(bufB, W2, dinv, bufA);
    k_agg<<<agg_blocks, 256, 0, stream>>>(bufA, rowptr, col, dinv, b2, bufB);
    // layer 3
    k_gemm<<<ggrid, 256, 0, stream>>>(bufB, W3, dinv, bufA);
    k_agg<<<agg_blocks, 256, 0, stream>>>(bufA, rowptr, col, dinv, b3, bufB);

    // pool + fc
    k_bounds<<<1, 256, 0, stream>>>(batch, gstart);
    k_pool<<<NG, 256, 0, stream>>>(bufB, gstart, pooled);
    k_fc<<<NG, 64, 0, stream>>>(pooled, Wfc, bfc, out);
}

// Round 2
// 947.659 us; speedup vs baseline: 1.3230x; 1.3230x over previous
//
#include <hip/hip_runtime.h>

#define NN 100000
#define NE 1600000
#define DF 128
#define DOUT 64
#define NG 128
#define NB 391  // ceil(NN/256)

// ---------------- graph preprocessing ----------------

__global__ void k_zero(int* __restrict__ cnt) {
    int i = blockIdx.x * blockDim.x + threadIdx.x;
    if (i < NN) cnt[i] = 0;
}

__global__ void k_hist(const int* __restrict__ dst, int* __restrict__ cnt) {
    int i = blockIdx.x * blockDim.x + threadIdx.x;
    if (i < NE) atomicAdd(&cnt[dst[i]], 1);
}

// phase 1: per-block sums of cnt
__global__ __launch_bounds__(256) void k_partial(const int* __restrict__ cnt,
                                                 int* __restrict__ bsum) {
    __shared__ int sh[256];
    int t = threadIdx.x;
    int idx = blockIdx.x * 256 + t;
    int v = (idx < NN) ? cnt[idx] : 0;
    sh[t] = v;
    __syncthreads();
    for (int off = 128; off > 0; off >>= 1) {
        if (t < off) sh[t] += sh[t + off];
        __syncthreads();
    }
    if (t == 0) bsum[blockIdx.x] = sh[0];
}

// phase 2: exclusive scan of NB block sums (1 block), also writes rowptr[NN]=total
__global__ __launch_bounds__(512) void k_scansums(const int* __restrict__ bsum,
                                                  int* __restrict__ boff,
                                                  int* __restrict__ rowptr) {
    __shared__ int sh[512];
    int t = threadIdx.x;
    int v = (t < NB) ? bsum[t] : 0;
    sh[t] = v;
    __syncthreads();
    for (int off = 1; off < 512; off <<= 1) {
        int a = (t >= off) ? sh[t - off] : 0;
        __syncthreads();
        sh[t] += a;
        __syncthreads();
    }
    if (t < NB) boff[t] = sh[t] - v;  // exclusive
    if (t == 511) rowptr[NN] = sh[511];
}

// phase 3: local exclusive scan + writeout (coalesced)
__global__ __launch_bounds__(256) void k_write(const int* __restrict__ cnt,
                                               const int* __restrict__ boff,
                                               int* __restrict__ rowptr,
                                               int* __restrict__ cursor,
                                               float* __restrict__ dinv) {
    __shared__ int sh[256];
    int t = threadIdx.x;
    int idx = blockIdx.x * 256 + t;
    int v = (idx < NN) ? cnt[idx] : 0;
    sh[t] = v;
    __syncthreads();
    for (int off = 1; off < 256; off <<= 1) {
        int a = (t >= off) ? sh[t - off] : 0;
        __syncthreads();
        sh[t] += a;
        __syncthreads();
    }
    if (idx < NN) {
        int excl = sh[t] - v + boff[blockIdx.x];
        rowptr[idx] = excl;
        cursor[idx] = excl;
        dinv[idx] = rsqrtf((float)(v + 1));  // +1 self-loop
    }
}

__global__ void k_fill(const int* __restrict__ src, const int* __restrict__ dst,
                       int* __restrict__ cursor, int* __restrict__ col) {
    int i = blockIdx.x * blockDim.x + threadIdx.x;
    if (i < NE) {
        int d = dst[i];
        int p = atomicAdd(&cursor[d], 1);
        col[p] = src[i];
    }
}

// ---------------- per-layer compute ----------------

// out[n][f] = dinv[n] * sum_k X[n][k] * W[k][f]   (64-row x 64-col tile per block)
__global__ __launch_bounds__(256) void k_gemm(const float* __restrict__ X,
                                              const float* __restrict__ W,
                                              const float* __restrict__ dinv,
                                              float* __restrict__ out) {
    __shared__ float xs[64][132];   // padded
    __shared__ float ws[128][64];
    int t = threadIdx.x;
    int row0 = blockIdx.x * 64;
    int cb = blockIdx.y * 64;

    for (int i = 0; i < 8; i++) {
        int li = t + i * 256;
        int k = li >> 4;
        int fq = li & 15;
        float4 v = *(const float4*)&W[k * DF + cb + fq * 4];
        *(float4*)&ws[k][fq * 4] = v;
    }
    for (int i = 0; i < 8; i++) {
        int li = t + i * 256;
        int r = li >> 5;
        int kq = li & 31;
        int gr = row0 + r;
        float4 v = make_float4(0.f, 0.f, 0.f, 0.f);
        if (gr < NN) v = *(const float4*)&X[gr * DF + kq * 4];
        *(float4*)&xs[r][kq * 4] = v;
    }
    __syncthreads();

    int tx = t & 15, ty = t >> 4;
    float acc[4][4] = {};
#pragma unroll 4
    for (int k = 0; k < 128; k++) {
        float4 wv = *(const float4*)&ws[k][tx * 4];
        float x0 = xs[ty * 4 + 0][k];
        float x1 = xs[ty * 4 + 1][k];
        float x2 = xs[ty * 4 + 2][k];
        float x3 = xs[ty * 4 + 3][k];
        acc[0][0] += x0 * wv.x; acc[0][1] += x0 * wv.y; acc[0][2] += x0 * wv.z; acc[0][3] += x0 * wv.w;
        acc[1][0] += x1 * wv.x; acc[1][1] += x1 * wv.y; acc[1][2] += x1 * wv.z; acc[1][3] += x1 * wv.w;
        acc[2][0] += x2 * wv.x; acc[2][1] += x2 * wv.y; acc[2][2] += x2 * wv.z; acc[2][3] += x2 * wv.w;
        acc[3][0] += x3 * wv.x; acc[3][1] += x3 * wv.y; acc[3][2] += x3 * wv.z; acc[3][3] += x3 * wv.w;
    }

    for (int j = 0; j < 4; j++) {
        int r = row0 + ty * 4 + j;
        if (r < NN) {
            float dv = dinv[r];
            float4 o;
            o.x = acc[j][0] * dv; o.y = acc[j][1] * dv;
            o.z = acc[j][2] * dv; o.w = acc[j][3] * dv;
            *(float4*)&out[r * DF + cb + tx * 4] = o;
        }
    }
}

// out[n] = relu(dinv[n] * (hs[n] + sum_{e in row n} hs[col[e]]) + b)
__global__ __launch_bounds__(256) void k_agg(const float* __restrict__ hs,
                                             const int* __restrict__ rowptr,
                                             const int* __restrict__ col,
                                             const float* __restrict__ dinv,
                                             const float* __restrict__ b,
                                             float* __restrict__ out) {
    int n = (int)((blockIdx.x * (size_t)blockDim.x + threadIdx.x) >> 6);
    int lane = threadIdx.x & 63;
    if (n >= NN) return;
    int f = lane * 2;
    float2 acc = *(const float2*)&hs[(size_t)n * DF + f];  // self-loop term
    int e = rowptr[n];
    int e1 = rowptr[n + 1];
    for (; e + 4 <= e1; e += 4) {
        int s0 = col[e], s1 = col[e + 1], s2 = col[e + 2], s3 = col[e + 3];
        float2 a0 = *(const float2*)&hs[(size_t)s0 * DF + f];
        float2 a1 = *(const float2*)&hs[(size_t)s1 * DF + f];
        float2 a2 = *(const float2*)&hs[(size_t)s2 * DF + f];
        float2 a3 = *(const float2*)&hs[(size_t)s3 * DF + f];
        acc.x += (a0.x + a1.x) + (a2.x + a3.x);
        acc.y += (a0.y + a1.y) + (a2.y + a3.y);
    }
    for (; e < e1; e++) {
        int s = col[e];
        float2 a = *(const float2*)&hs[(size_t)s * DF + f];
        acc.x += a.x; acc.y += a.y;
    }
    float dv = dinv[n];
    float2 bb = *(const float2*)&b[f];
    float2 o;
    o.x = fmaxf(dv * acc.x + bb.x, 0.f);
    o.y = fmaxf(dv * acc.y + bb.y, 0.f);
    *(float2*)&out[(size_t)n * DF + f] = o;
}

// ---------------- pooling + FC ----------------

__global__ void k_bounds(const int* __restrict__ batch, int* __restrict__ gstart) {
    int g = threadIdx.x;
    if (g > NG) return;
    int lo = 0, hi = NN;
    while (lo < hi) {
        int mid = (lo + hi) >> 1;
        if (batch[mid] < g) lo = mid + 1; else hi = mid;
    }
    gstart[g] = lo;
}

__global__ __launch_bounds__(256) void k_pool(const float* __restrict__ h,
                                              const int* __restrict__ gstart,
                                              float* __restrict__ pooled) {
    __shared__ float red[256];
    int g = blockIdx.x;
    int t = threadIdx.x;
    int f = t & 127, half = t >> 7;
    int s = gstart[g], epos = gstart[g + 1];
    float acc = 0.f;
    for (int n = s + half; n < epos; n += 2) acc += h[(size_t)n * DF + f];
    red[t] = acc;
    __syncthreads();
    if (t < 128) {
        int c = epos - s;
        float tot = red[t] + red[t + 128];
        pooled[g * DF + f] = tot / (float)max(c, 1);
    }
}

__global__ __launch_bounds__(64) void k_fc(const float* __restrict__ pooled,
                                           const float* __restrict__ Wfc,
                                           const float* __restrict__ bfc,
                                           float* __restrict__ out) {
    int g = blockIdx.x;
    int o = threadIdx.x;
    float acc = bfc[o];
    for (int k = 0; k < DF; k++) acc += pooled[g * DF + k] * Wfc[k * DOUT + o];
    out[g * DOUT + o] = acc;
}

// ---------------- launch ----------------

extern "C" void kernel_launch(void* const* d_in, const int* in_sizes, int n_in,
                              void* d_out, int out_size, void* d_ws, size_t ws_size,
                              hipStream_t stream) {
    const float* x     = (const float*)d_in[0];
    const int*   ei    = (const int*)d_in[1];   // [2, NE] flattened: src then dst
    const int*   batch = (const int*)d_in[2];
    const float* W1 = (const float*)d_in[3];
    const float* b1 = (const float*)d_in[4];
    const float* W2 = (const float*)d_in[5];
    const float* b2 = (const float*)d_in[6];
    const float* W3 = (const float*)d_in[7];
    const float* b3 = (const float*)d_in[8];
    const float* Wfc = (const float*)d_in[9];
    const float* bfc = (const float*)d_in[10];
    float* out = (float*)d_out;

    char* p = (char*)d_ws;
    float* bufA = (float*)p;           p += (size_t)NN * DF * sizeof(float);
    float* bufB = (float*)p;           p += (size_t)NN * DF * sizeof(float);
    float* dinv = (float*)p;           p += (size_t)NN * sizeof(float);
    int* cnt    = (int*)p;             p += (size_t)NN * sizeof(int);
    int* rowptr = (int*)p;             p += (size_t)(NN + 4) * sizeof(int);
    int* cursor = (int*)p;             p += (size_t)NN * sizeof(int);
    int* col    = (int*)p;             p += (size_t)NE * sizeof(int);
    int* gstart = (int*)p;             p += (size_t)(NG + 4) * sizeof(int);
    float* pooled = (float*)p;         p += (size_t)NG * DF * sizeof(float);
    int* bsum   = (int*)p;             p += (size_t)(NB + 4) * sizeof(int);
    int* boff   = (int*)p;             p += (size_t)(NB + 4) * sizeof(int);

    const int* e_src = ei;
    const int* e_dst = ei + NE;

    // graph preprocessing (CSR by dst, no self-loop edges stored)
    k_zero<<<(NN + 255) / 256, 256, 0, stream>>>(cnt);
    k_hist<<<(NE + 255) / 256, 256, 0, stream>>>(e_dst, cnt);
    k_partial<<<NB, 256, 0, stream>>>(cnt, bsum);
    k_scansums<<<1, 512, 0, stream>>>(bsum, boff, rowptr);
    k_write<<<NB, 256, 0, stream>>>(cnt, boff, rowptr, cursor, dinv);
    k_fill<<<(NE + 255) / 256, 256, 0, stream>>>(e_src, e_dst, cursor, col);

    dim3 ggrid((NN + 63) / 64, 2);
    int agg_blocks = (NN + 3) / 4;  // one wave per node, 4 waves/block

    // layer 1
    k_gemm<<<ggrid, 256, 0, stream>>>(x, W1, dinv, bufA);
    k_agg<<<agg_blocks, 256, 0, stream>>>(bufA, rowptr, col, dinv, b1, bufB);
    // layer 2
    k_gemm<<<ggrid, 256, 0, stream>>>(bufB, W2, dinv, bufA);
    k_agg<<<agg_blocks, 256, 0, stream>>>(bufA, rowptr, col, dinv, b2, bufB);
    // layer 3
    k_gemm<<<ggrid, 256, 0, stream>>>(bufB, W3, dinv, bufA);
    k_agg<<<agg_blocks, 256, 0, stream>>>(bufA, rowptr, col, dinv, b3, bufB);

    // pool + fc
    k_bounds<<<1, 256, 0, stream>>>(batch, gstart);
    k_pool<<<NG, 256, 0, stream>>>(bufB, gstart, pooled);
    k_fc<<<NG, 64, 0, stream>>>(pooled, Wfc, bfc, out);
}

// Round 3
// 686.051 us; speedup vs baseline: 1.8275x; 1.3813x over previous
//
#include <hip/hip_runtime.h>

#define NN 100000
#define NE 1600000
#define DF 128
#define DOUT 64
#define NG 128
#define NB 391  // ceil(NN/256)

typedef short short8 __attribute__((ext_vector_type(8)));
typedef float floatx4 __attribute__((ext_vector_type(4)));

__device__ __forceinline__ unsigned short f2bf(float f) {
    unsigned int b = __float_as_uint(f);
    unsigned int r = (b + 0x7fffu + ((b >> 16) & 1u)) >> 16;
    return (unsigned short)r;
}
__device__ __forceinline__ float bf2f_lo(unsigned int v) { return __uint_as_float(v << 16); }
__device__ __forceinline__ float bf2f_hi(unsigned int v) { return __uint_as_float(v & 0xffff0000u); }

// ---------------- graph preprocessing ----------------

__global__ void k_zero(int* __restrict__ cnt) {
    int i = blockIdx.x * blockDim.x + threadIdx.x;
    if (i < NN) cnt[i] = 0;
}

__global__ void k_hist(const int* __restrict__ dst, int* __restrict__ cnt) {
    int i = blockIdx.x * blockDim.x + threadIdx.x;
    if (i < NE) atomicAdd(&cnt[dst[i]], 1);
}

__global__ __launch_bounds__(256) void k_partial(const int* __restrict__ cnt,
                                                 int* __restrict__ bsum) {
    __shared__ int sh[256];
    int t = threadIdx.x;
    int idx = blockIdx.x * 256 + t;
    int v = (idx < NN) ? cnt[idx] : 0;
    sh[t] = v;
    __syncthreads();
    for (int off = 128; off > 0; off >>= 1) {
        if (t < off) sh[t] += sh[t + off];
        __syncthreads();
    }
    if (t == 0) bsum[blockIdx.x] = sh[0];
}

__global__ __launch_bounds__(512) void k_scansums(const int* __restrict__ bsum,
                                                  int* __restrict__ boff,
                                                  int* __restrict__ rowptr) {
    __shared__ int sh[512];
    int t = threadIdx.x;
    int v = (t < NB) ? bsum[t] : 0;
    sh[t] = v;
    __syncthreads();
    for (int off = 1; off < 512; off <<= 1) {
        int a = (t >= off) ? sh[t - off] : 0;
        __syncthreads();
        sh[t] += a;
        __syncthreads();
    }
    if (t < NB) boff[t] = sh[t] - v;
    if (t == 511) rowptr[NN] = sh[511];
}

__global__ __launch_bounds__(256) void k_write(const int* __restrict__ cnt,
                                               const int* __restrict__ boff,
                                               int* __restrict__ rowptr,
                                               int* __restrict__ cursor,
                                               float* __restrict__ dinv) {
    __shared__ int sh[256];
    int t = threadIdx.x;
    int idx = blockIdx.x * 256 + t;
    int v = (idx < NN) ? cnt[idx] : 0;
    sh[t] = v;
    __syncthreads();
    for (int off = 1; off < 256; off <<= 1) {
        int a = (t >= off) ? sh[t - off] : 0;
        __syncthreads();
        sh[t] += a;
        __syncthreads();
    }
    if (idx < NN) {
        int excl = sh[t] - v + boff[blockIdx.x];
        rowptr[idx] = excl;
        cursor[idx] = excl;
        dinv[idx] = rsqrtf((float)(v + 1));
    }
}

__global__ void k_fill(const int* __restrict__ src, const int* __restrict__ dst,
                       int* __restrict__ cursor, int* __restrict__ col) {
    int i = blockIdx.x * blockDim.x + threadIdx.x;
    if (i < NE) {
        int d = dst[i];
        int p = atomicAdd(&cursor[d], 1);
        col[p] = src[i];
    }
}

// ---------------- bf16 conversions ----------------

// W (128x128 f32, row-major) -> fragment-ordered bf16:
// Wb[((t*4+s)*64 + l)*8 + j] = W[s*32 + (l>>4)*8 + j][t*16 + (l&15)]
__global__ __launch_bounds__(256) void k_prepw(const float* __restrict__ W,
                                               unsigned short* __restrict__ Wb) {
    int idx = blockIdx.x * 256 + threadIdx.x;
    if (idx >= 2048) return;
    int l = idx & 63;
    int s = (idx >> 6) & 3;
    int t = idx >> 8;
    int k0 = s * 32 + (l >> 4) * 8;
    int c = t * 16 + (l & 15);
    unsigned short o[8];
#pragma unroll
    for (int j = 0; j < 8; j++) o[j] = f2bf(W[(k0 + j) * DF + c]);
    *(short8*)&Wb[idx * 8] = *(short8*)o;
}

// x f32 -> bf16, 8 elems/thread
__global__ __launch_bounds__(256) void k_prepx(const float* __restrict__ x,
                                               unsigned short* __restrict__ xb) {
    size_t i = ((size_t)blockIdx.x * 256 + threadIdx.x) * 8;
    if (i >= (size_t)NN * DF) return;
    float4 a = *(const float4*)&x[i];
    float4 b = *(const float4*)&x[i + 4];
    unsigned short o[8] = {f2bf(a.x), f2bf(a.y), f2bf(a.z), f2bf(a.w),
                           f2bf(b.x), f2bf(b.y), f2bf(b.z), f2bf(b.w)};
    *(short8*)&xb[i] = *(short8*)o;
}

// ---------------- per-layer compute ----------------

// hs[n][f] = bf16( dinv[n] * sum_k X[n][k]*W[k][f] ), MFMA 16x16x32 bf16
// wave handles 16 rows x 128 cols; block = 4 waves = 64 rows
__global__ __launch_bounds__(256) void k_gemm(const unsigned short* __restrict__ X,
                                              const unsigned short* __restrict__ Wb,
                                              const float* __restrict__ dinv,
                                              unsigned short* __restrict__ hs) {
    int t = threadIdx.x;
    int wave = t >> 6, l = t & 63;
    int r0 = blockIdx.x * 64 + wave * 16;
    int lm = l & 15, q = l >> 4;

    int arow = r0 + lm;
    if (arow >= NN) arow = NN - 1;  // clamped read; stores guarded below
    const unsigned short* xrow = X + (size_t)arow * DF + q * 8;
    short8 af0 = *(const short8*)(xrow);
    short8 af1 = *(const short8*)(xrow + 32);
    short8 af2 = *(const short8*)(xrow + 64);
    short8 af3 = *(const short8*)(xrow + 96);

    int orow = r0 + q * 4;  // this lane's 4 output rows
    float dv[4];
#pragma unroll
    for (int j = 0; j < 4; j++) dv[j] = (orow + j < NN) ? dinv[orow + j] : 0.f;

#pragma unroll
    for (int tt = 0; tt < 8; tt++) {
        floatx4 acc = {0.f, 0.f, 0.f, 0.f};
        const unsigned short* wp = Wb + ((size_t)(tt * 4) * 64 + l) * 8;
        acc = __builtin_amdgcn_mfma_f32_16x16x32_bf16(af0, *(const short8*)(wp), acc, 0, 0, 0);
        acc = __builtin_amdgcn_mfma_f32_16x16x32_bf16(af1, *(const short8*)(wp + 512), acc, 0, 0, 0);
        acc = __builtin_amdgcn_mfma_f32_16x16x32_bf16(af2, *(const short8*)(wp + 1024), acc, 0, 0, 0);
        acc = __builtin_amdgcn_mfma_f32_16x16x32_bf16(af3, *(const short8*)(wp + 1536), acc, 0, 0, 0);
        int c = tt * 16 + lm;
#pragma unroll
        for (int j = 0; j < 4; j++) {
            int r = orow + j;
            if (r < NN) hs[(size_t)r * DF + c] = f2bf(acc[j] * dv[j]);
        }
    }
}

// out[n] = bf16( relu(dinv[n] * (hs[n] + sum_edges hs[col[e]]) + b) )
__global__ __launch_bounds__(256) void k_agg(const unsigned short* __restrict__ hs,
                                             const int* __restrict__ rowptr,
                                             const int* __restrict__ col,
                                             const float* __restrict__ dinv,
                                             const float* __restrict__ b,
                                             unsigned short* __restrict__ out) {
    int n = (int)((blockIdx.x * (size_t)blockDim.x + threadIdx.x) >> 6);
    int lane = threadIdx.x & 63;
    if (n >= NN) return;
    int f = lane * 2;
    unsigned int sv = *(const unsigned int*)&hs[(size_t)n * DF + f];
    float ax = bf2f_lo(sv), ay = bf2f_hi(sv);
    int e = rowptr[n];
    int e1 = rowptr[n + 1];
    for (; e + 4 <= e1; e += 4) {
        int s0 = col[e], s1 = col[e + 1], s2 = col[e + 2], s3 = col[e + 3];
        unsigned int v0 = *(const unsigned int*)&hs[(size_t)s0 * DF + f];
        unsigned int v1 = *(const unsigned int*)&hs[(size_t)s1 * DF + f];
        unsigned int v2 = *(const unsigned int*)&hs[(size_t)s2 * DF + f];
        unsigned int v3 = *(const unsigned int*)&hs[(size_t)s3 * DF + f];
        ax += (bf2f_lo(v0) + bf2f_lo(v1)) + (bf2f_lo(v2) + bf2f_lo(v3));
        ay += (bf2f_hi(v0) + bf2f_hi(v1)) + (bf2f_hi(v2) + bf2f_hi(v3));
    }
    for (; e < e1; e++) {
        unsigned int v = *(const unsigned int*)&hs[(size_t)col[e] * DF + f];
        ax += bf2f_lo(v);
        ay += bf2f_hi(v);
    }
    float dvn = dinv[n];
    float2 bb = *(const float2*)&b[f];
    float ox = fmaxf(dvn * ax + bb.x, 0.f);
    float oy = fmaxf(dvn * ay + bb.y, 0.f);
    unsigned int packed = (unsigned int)f2bf(ox) | ((unsigned int)f2bf(oy) << 16);
    *(unsigned int*)&out[(size_t)n * DF + f] = packed;
}

// ---------------- pooling + FC ----------------

__global__ void k_bounds(const int* __restrict__ batch, int* __restrict__ gstart) {
    int g = threadIdx.x;
    if (g > NG) return;
    int lo = 0, hi = NN;
    while (lo < hi) {
        int mid = (lo + hi) >> 1;
        if (batch[mid] < g) lo = mid + 1; else hi = mid;
    }
    gstart[g] = lo;
}

__global__ __launch_bounds__(256) void k_pool(const unsigned short* __restrict__ h,
                                              const int* __restrict__ gstart,
                                              float* __restrict__ pooled) {
    __shared__ float red[256];
    int g = blockIdx.x;
    int t = threadIdx.x;
    int f = t & 127, half = t >> 7;
    int s = gstart[g], epos = gstart[g + 1];
    float acc = 0.f;
    for (int n = s + half; n < epos; n += 2)
        acc += __uint_as_float((unsigned int)h[(size_t)n * DF + f] << 16);
    red[t] = acc;
    __syncthreads();
    if (t < 128) {
        int c = epos - s;
        float tot = red[t] + red[t + 128];
        pooled[g * DF + f] = tot / (float)max(c, 1);
    }
}

__global__ __launch_bounds__(64) void k_fc(const float* __restrict__ pooled,
                                           const float* __restrict__ Wfc,
                                           const float* __restrict__ bfc,
                                           float* __restrict__ out) {
    int g = blockIdx.x;
    int o = threadIdx.x;
    float acc = bfc[o];
    for (int k = 0; k < DF; k++) acc += pooled[g * DF + k] * Wfc[k * DOUT + o];
    out[g * DOUT + o] = acc;
}

// ---------------- launch ----------------

extern "C" void kernel_launch(void* const* d_in, const int* in_sizes, int n_in,
                              void* d_out, int out_size, void* d_ws, size_t ws_size,
                              hipStream_t stream) {
    const float* x     = (const float*)d_in[0];
    const int*   ei    = (const int*)d_in[1];
    const int*   batch = (const int*)d_in[2];
    const float* W1 = (const float*)d_in[3];
    const float* b1 = (const float*)d_in[4];
    const float* W2 = (const float*)d_in[5];
    const float* b2 = (const float*)d_in[6];
    const float* W3 = (const float*)d_in[7];
    const float* b3 = (const float*)d_in[8];
    const float* Wfc = (const float*)d_in[9];
    const float* bfc = (const float*)d_in[10];
    float* out = (float*)d_out;

    char* p = (char*)d_ws;
    unsigned short* xb = (unsigned short*)p;  p += (size_t)NN * DF * sizeof(short);
    unsigned short* hs = (unsigned short*)p;  p += (size_t)NN * DF * sizeof(short);
    unsigned short* ob = (unsigned short*)p;  p += (size_t)NN * DF * sizeof(short);
    unsigned short* Wb1 = (unsigned short*)p; p += 16384 * sizeof(short);
    unsigned short* Wb2 = (unsigned short*)p; p += 16384 * sizeof(short);
    unsigned short* Wb3 = (unsigned short*)p; p += 16384 * sizeof(short);
    float* dinv = (float*)p;           p += (size_t)NN * sizeof(float);
    int* cnt    = (int*)p;             p += (size_t)NN * sizeof(int);
    int* rowptr = (int*)p;             p += (size_t)(NN + 4) * sizeof(int);
    int* cursor = (int*)p;             p += (size_t)NN * sizeof(int);
    int* col    = (int*)p;             p += (size_t)NE * sizeof(int);
    int* gstart = (int*)p;             p += (size_t)(NG + 4) * sizeof(int);
    float* pooled = (float*)p;         p += (size_t)NG * DF * sizeof(float);
    int* bsum   = (int*)p;             p += (size_t)(NB + 4) * sizeof(int);
    int* boff   = (int*)p;             p += (size_t)(NB + 4) * sizeof(int);

    const int* e_src = ei;
    const int* e_dst = ei + NE;

    // graph preprocessing (CSR by dst)
    k_zero<<<(NN + 255) / 256, 256, 0, stream>>>(cnt);
    k_hist<<<(NE + 255) / 256, 256, 0, stream>>>(e_dst, cnt);
    k_partial<<<NB, 256, 0, stream>>>(cnt, bsum);
    k_scansums<<<1, 512, 0, stream>>>(bsum, boff, rowptr);
    k_write<<<NB, 256, 0, stream>>>(cnt, boff, rowptr, cursor, dinv);
    k_fill<<<(NE + 255) / 256, 256, 0, stream>>>(e_src, e_dst, cursor, col);

    // bf16 conversions
    k_prepw<<<8, 256, 0, stream>>>(W1, Wb1);
    k_prepw<<<8, 256, 0, stream>>>(W2, Wb2);
    k_prepw<<<8, 256, 0, stream>>>(W3, Wb3);
    k_prepx<<<(NN * DF / 8 + 255) / 256, 256, 0, stream>>>(x, xb);

    int ggrid = (NN + 63) / 64;
    int agg_blocks = (NN + 3) / 4;

    // layer 1
    k_gemm<<<ggrid, 256, 0, stream>>>(xb, Wb1, dinv, hs);
    k_agg<<<agg_blocks, 256, 0, stream>>>(hs, rowptr, col, dinv, b1, ob);
    // layer 2
    k_gemm<<<ggrid, 256, 0, stream>>>(ob, Wb2, dinv, hs);
    k_agg<<<agg_blocks, 256, 0, stream>>>(hs, rowptr, col, dinv, b2, ob);
    // layer 3
    k_gemm<<<ggrid, 256, 0, stream>>>(ob, Wb3, dinv, hs);
    k_agg<<<agg_blocks, 256, 0, stream>>>(hs, rowptr, col, dinv, b3, ob);

    // pool + fc
    k_bounds<<<1, 256, 0, stream>>>(batch, gstart);
    k_pool<<<NG, 256, 0, stream>>>(ob, gstart, pooled);
    k_fc<<<NG, 64, 0, stream>>>(pooled, Wfc, bfc, out);
}